// Round 8
// baseline (1842.707 us; speedup 1.0000x reference)
//
#include <hip/hip_runtime.h>
#include <math.h>

#define Bn   8
#define Cn   256
#define HWn  4096
#define FB   (Cn * HWn)      // 1048576 elems per batch-field
#define NTOT (Bn * FB)       // 8388608 elems per field
#define TEND 1.0
#define EPSK 1e-12f
#define NT   64              // apply N-tile (positions)
#define RS   56              // P LDS row stride (bf16)

typedef float f32x4 __attribute__((ext_vector_type(4)));
typedef short bf16x8 __attribute__((ext_vector_type(8)));

__device__ inline float b2f(unsigned int u) { return __uint_as_float(u << 16); }
__device__ inline unsigned short f2b(float f) {  // RNE
    unsigned u = __float_as_uint(f);
    unsigned r = u + 0x7FFFu + ((u >> 16) & 1u);
    return (unsigned short)(r >> 16);
}
__device__ inline void unp8(uint4 u, float* f) {
    f[0] = b2f(u.x & 0xFFFFu); f[1] = b2f(u.x >> 16);
    f[2] = b2f(u.y & 0xFFFFu); f[3] = b2f(u.y >> 16);
    f[4] = b2f(u.z & 0xFFFFu); f[5] = b2f(u.z >> 16);
    f[6] = b2f(u.w & 0xFFFFu); f[7] = b2f(u.w >> 16);
}

// acc layout (floats, 8 batches each):
//   D[k][j] at acc[(k*8+j)*8 + b];  Nsq[j] at acc[512 + j*8 + b];  coords at acc+576
// Scale bookkeeping (expm, fp64): m_0=sqrt(Nsq0); m_j=sqrt(Nsqj)+EPS*m_{j-1}
//   H[j][k]=D[k][j]/(m_j m_k); H[k+1][k]=sqrt(Nsq[k+1])/m_k; coeff_j=expm[j][8]*m_0/m_j

__global__ void init_kernel(float* __restrict__ p) {
    for (int i = threadIdx.x; i < 1024; i += 256) p[i] = 0.0f;
}

// ---- split W into bf16 hi/lo in MFMA-A staged layout ----
__global__ void wsplit_kernel(const float* __restrict__ W,
                              unsigned short* __restrict__ Whs,
                              unsigned short* __restrict__ Wls) {
    int kc = blockIdx.x, mt = blockIdx.y, l = threadIdx.x;
    int m = mt * 16 + (l & 15);
    int k0 = kc * 32 + (l >> 4) * 8;
#pragma unroll
    for (int j = 0; j < 8; ++j) {
        float wv = W[m * 256 + k0 + j];
        unsigned short h = f2b(wv);
        unsigned short lo = f2b(wv - b2f(h));
        int idx = ((kc * 16 + mt) * 64 + l) * 8 + j;
        Whs[idx] = h; Wls[idx] = lo;
    }
}

// ---- U_0 = bf16(v); Nsq[0] = ||U_0||^2 ----
__global__ __launch_bounds__(256) void v2bf_kernel(const float* __restrict__ v,
                                                   unsigned short* __restrict__ U0,
                                                   float* __restrict__ acc) {
    int b = blockIdx.y;
    const size_t boff = (size_t)b * FB;
    const float4* vv = (const float4*)(v + boff);
    uint4* uo = (uint4*)(U0 + boff);
    int i = blockIdx.x * 256 + threadIdx.x;   // grid.x=128 -> 32768/batch
    float np = 0.f;
#pragma unroll
    for (int r = 0; r < 4; ++r) {
        int idx = i + r * 32768;
        float4 a = vv[2 * idx], c = vv[2 * idx + 1];
        float e[8] = {a.x, a.y, a.z, a.w, c.x, c.y, c.z, c.w};
        unsigned int h[8];
#pragma unroll
        for (int k = 0; k < 8; ++k) {
            h[k] = f2b(e[k]);
            float xr = b2f(h[k]);
            np = fmaf(xr, xr, np);
        }
        uint4 o;
        o.x = h[0] | (h[1] << 16); o.y = h[2] | (h[3] << 16);
        o.z = h[4] | (h[5] << 16); o.w = h[6] | (h[7] << 16);
        uo[idx] = o;
    }
    for (int off = 32; off > 0; off >>= 1) np += __shfl_down(np, off);
    __shared__ float red[4];
    int lane = threadIdx.x & 63, wid = threadIdx.x >> 6;
    if (lane == 0) red[wid] = np;
    __syncthreads();
    if (threadIdx.x == 0) atomicAdd(&acc[512 + b], red[0] + red[1] + red[2] + red[3]);
}

// ---- Z = W @ s0 (fp32 out), MFMA hi/lo ----
__global__ __launch_bounds__(256, 3) void z_kernel(const float* __restrict__ s0,
        const unsigned short* __restrict__ Whs, const unsigned short* __restrict__ Wls,
        float* __restrict__ Zb) {
    __shared__ short Ah[8192], Al[8192];
    __shared__ short Ph[NT * RS], Pl[NT * RS];
    const int tid = threadIdx.x;
    const int b = blockIdx.y;
    const int sbase = blockIdx.x * NT;
    const size_t boff = (size_t)b * FB;
    const int lane = tid & 63, wq = tid >> 6;
    const int mbase = wq * 64;
    f32x4 dacc[4][4];
#pragma unroll
    for (int i = 0; i < 4; ++i)
#pragma unroll
        for (int j = 0; j < 4; ++j) dacc[i][j] = (f32x4){0.f, 0.f, 0.f, 0.f};
    const int cg = tid >> 4, pos = (tid & 15) * 4;
    for (int kc = 0; kc < 8; ++kc) {
        __syncthreads();
        {
            const uint4* srcH = (const uint4*)(Whs + kc * 8192);
            const uint4* srcL = (const uint4*)(Wls + kc * 8192);
            uint4* dH = (uint4*)Ah; uint4* dL = (uint4*)Al;
#pragma unroll
            for (int i = 0; i < 4; ++i) {
                dH[tid + i * 256] = srcH[tid + i * 256];
                dL[tid + i * 256] = srcL[tid + i * 256];
            }
        }
#pragma unroll
        for (int ci = 0; ci < 2; ++ci) {
            int cl = ci * 16 + cg;
            int c = kc * 32 + cl;
            size_t off = boff + (size_t)c * HWn + sbase + pos;
            float4 sv = *(const float4*)(s0 + off);
            float p[4] = {sv.x, sv.y, sv.z, sv.w};
#pragma unroll
            for (int i = 0; i < 4; ++i) {
                unsigned short h = f2b(p[i]);
                unsigned short l = f2b(p[i] - b2f(h));
                Ph[(pos + i) * RS + cl] = (short)h;
                Pl[(pos + i) * RS + cl] = (short)l;
            }
        }
        __syncthreads();
        bf16x8 ah[4], al[4], bh[4], bl[4];
#pragma unroll
        for (int rt = 0; rt < 4; ++rt) {
            int mt = (mbase >> 4) + rt;
            ah[rt] = *(bf16x8*)(Ah + (mt * 64 + lane) * 8);
            al[rt] = *(bf16x8*)(Al + (mt * 64 + lane) * 8);
        }
#pragma unroll
        for (int ct = 0; ct < 4; ++ct) {
            int n = ct * 16 + (lane & 15);
            int k8 = (lane >> 4) * 8;
            bh[ct] = *(bf16x8*)(Ph + n * RS + k8);
            bl[ct] = *(bf16x8*)(Pl + n * RS + k8);
        }
#pragma unroll
        for (int rt = 0; rt < 4; ++rt)
#pragma unroll
            for (int ct = 0; ct < 4; ++ct) {
                dacc[rt][ct] = __builtin_amdgcn_mfma_f32_16x16x32_bf16(ah[rt], bh[ct], dacc[rt][ct], 0, 0, 0);
                dacc[rt][ct] = __builtin_amdgcn_mfma_f32_16x16x32_bf16(ah[rt], bl[ct], dacc[rt][ct], 0, 0, 0);
                dacc[rt][ct] = __builtin_amdgcn_mfma_f32_16x16x32_bf16(al[rt], bh[ct], dacc[rt][ct], 0, 0, 0);
            }
    }
#pragma unroll
    for (int rt = 0; rt < 4; ++rt)
#pragma unroll
        for (int ct = 0; ct < 4; ++ct) {
            int s = sbase + ct * 16 + (lane & 15);
            int r0 = mbase + rt * 16 + (lane >> 4) * 4;
#pragma unroll
            for (int reg = 0; reg < 4; ++reg)
                Zb[boff + (size_t)(r0 + reg) * HWn + s] = dacc[rt][ct][reg];
        }
}

// ================= fully fused Krylov step K =================
// staging: x = w - sum_{j<K} c_j U_j (bf16 basis), write U_K bf16, Nsq[K]; P = s0*x (hi/lo LDS)
// MFMA: G = W @ P (3-product bf16 split)
// epilogue: w' = G - Z.*t; store w'; D[K][j] = <U_j, w'> for j<=K (w' in registers!)
template <int K>
__global__ __launch_bounds__(256, 3) void fused_step(
        const float* win,                      // prev A-output (K>=1); ignored K=0
        unsigned short* Qb,                    // U_j bf16 at j*NTOT; writes U_K
        const float* __restrict__ s0,
        const unsigned short* __restrict__ Whs,
        const unsigned short* __restrict__ Wls,
        const float* __restrict__ Zb,
        float* wout,                           // aliases win
        float* __restrict__ acc) {
    constexpr int KP = (K > 0) ? K : 1;
    __shared__ short Ah[8192], Al[8192];
    __shared__ short Ph[NT * RS], Pl[NT * RS];
    __shared__ float tred[16 * 64];
    __shared__ float ts[64];
    __shared__ float redn[4];
    __shared__ float redd[4][K + 1];
    const int tid = threadIdx.x;
    const int b = blockIdx.y;
    const int sbase = blockIdx.x * NT;
    const size_t boff = (size_t)b * FB;
    const int lane = tid & 63, wq = tid >> 6;
    const int mbase = wq * 64;

    float cj[KP];
    if constexpr (K > 0) {
        float m[KP];
        m[0] = sqrtf(acc[512 + b]);
#pragma unroll
        for (int j = 1; j < K; ++j) m[j] = sqrtf(acc[512 + j * 8 + b]) + EPSK * m[j - 1];
#pragma unroll
        for (int j = 0; j < K; ++j)
            cj[j] = acc[((K - 1) * 8 + j) * 8 + b] / (m[j] * m[j]);
    } else cj[0] = 0.f;

    f32x4 dacc[4][4];
#pragma unroll
    for (int i = 0; i < 4; ++i)
#pragma unroll
        for (int j = 0; j < 4; ++j) dacc[i][j] = (f32x4){0.f, 0.f, 0.f, 0.f};
    const int cg = tid >> 4, pos = (tid & 15) * 4;
    float tp[4] = {0.f, 0.f, 0.f, 0.f};
    float np = 0.f;

    for (int kc = 0; kc < 8; ++kc) {
        __syncthreads();
        {
            const uint4* srcH = (const uint4*)(Whs + kc * 8192);
            const uint4* srcL = (const uint4*)(Wls + kc * 8192);
            uint4* dH = (uint4*)Ah; uint4* dL = (uint4*)Al;
#pragma unroll
            for (int i = 0; i < 4; ++i) {
                dH[tid + i * 256] = srcH[tid + i * 256];
                dL[tid + i * 256] = srcL[tid + i * 256];
            }
        }
#pragma unroll
        for (int ci = 0; ci < 2; ++ci) {
            int cl = ci * 16 + cg;
            int c = kc * 32 + cl;
            size_t off = boff + (size_t)c * HWn + sbase + pos;
            float4 sv = *(const float4*)(s0 + off);
            float xr[4];
            if constexpr (K == 0) {
                ushort4 u0 = *(const ushort4*)(Qb + off);
                xr[0] = b2f(u0.x); xr[1] = b2f(u0.y);
                xr[2] = b2f(u0.z); xr[3] = b2f(u0.w);
            } else {
                ushort4 uu[KP];
#pragma unroll
                for (int j = 0; j < K; ++j)
                    uu[j] = *(const ushort4*)(Qb + (size_t)j * NTOT + off);
                float4 wv4 = *(const float4*)(win + off);
                float x[4] = {wv4.x, wv4.y, wv4.z, wv4.w};
#pragma unroll
                for (int j = 0; j < K; ++j) {
                    x[0] = fmaf(-cj[j], b2f(uu[j].x), x[0]);
                    x[1] = fmaf(-cj[j], b2f(uu[j].y), x[1]);
                    x[2] = fmaf(-cj[j], b2f(uu[j].z), x[2]);
                    x[3] = fmaf(-cj[j], b2f(uu[j].w), x[3]);
                }
                ushort4 st;
                st.x = f2b(x[0]); st.y = f2b(x[1]);
                st.z = f2b(x[2]); st.w = f2b(x[3]);
                *(ushort4*)(Qb + (size_t)K * NTOT + off) = st;
                xr[0] = b2f(st.x); xr[1] = b2f(st.y);
                xr[2] = b2f(st.z); xr[3] = b2f(st.w);
#pragma unroll
                for (int i = 0; i < 4; ++i) np = fmaf(xr[i], xr[i], np);
            }
            float se[4] = {sv.x, sv.y, sv.z, sv.w};
#pragma unroll
            for (int i = 0; i < 4; ++i) {
                float p = se[i] * xr[i];
                tp[i] += p;
                unsigned short h = f2b(p);
                unsigned short l = f2b(p - b2f(h));
                Ph[(pos + i) * RS + cl] = (short)h;
                Pl[(pos + i) * RS + cl] = (short)l;
            }
        }
        __syncthreads();
        bf16x8 ah[4], al[4], bh[4], bl[4];
#pragma unroll
        for (int rt = 0; rt < 4; ++rt) {
            int mt = (mbase >> 4) + rt;
            ah[rt] = *(bf16x8*)(Ah + (mt * 64 + lane) * 8);
            al[rt] = *(bf16x8*)(Al + (mt * 64 + lane) * 8);
        }
#pragma unroll
        for (int ct = 0; ct < 4; ++ct) {
            int n = ct * 16 + (lane & 15);
            int k8 = (lane >> 4) * 8;
            bh[ct] = *(bf16x8*)(Ph + n * RS + k8);
            bl[ct] = *(bf16x8*)(Pl + n * RS + k8);
        }
#pragma unroll
        for (int rt = 0; rt < 4; ++rt)
#pragma unroll
            for (int ct = 0; ct < 4; ++ct) {
                dacc[rt][ct] = __builtin_amdgcn_mfma_f32_16x16x32_bf16(ah[rt], bh[ct], dacc[rt][ct], 0, 0, 0);
                dacc[rt][ct] = __builtin_amdgcn_mfma_f32_16x16x32_bf16(ah[rt], bl[ct], dacc[rt][ct], 0, 0, 0);
                dacc[rt][ct] = __builtin_amdgcn_mfma_f32_16x16x32_bf16(al[rt], bh[ct], dacc[rt][ct], 0, 0, 0);
            }
    }
    // t reduction + Nsq[K]
#pragma unroll
    for (int i = 0; i < 4; ++i) tred[cg * 64 + pos + i] = tp[i];
    if constexpr (K > 0) {
        for (int o2 = 32; o2 > 0; o2 >>= 1) np += __shfl_down(np, o2);
        if (lane == 0) redn[wq] = np;
    }
    __syncthreads();
    if (tid < 64) {
        float s = 0.f;
#pragma unroll
        for (int g = 0; g < 16; ++g) s += tred[g * 64 + tid];
        ts[tid] = s;
    }
    if (K > 0 && tid == 0)
        atomicAdd(&acc[512 + K * 8 + b], redn[0] + redn[1] + redn[2] + redn[3]);
    __syncthreads();
    // epilogue: w' = G - Z*t, store; fused dots D[K][j] = <U_j, w'>
    float pd[K + 1];
#pragma unroll
    for (int j = 0; j <= K; ++j) pd[j] = 0.f;
#pragma unroll
    for (int rt = 0; rt < 4; ++rt)
#pragma unroll
        for (int ct = 0; ct < 4; ++ct) {
            int sl = ct * 16 + (lane & 15);
            int s = sbase + sl;
            int r0 = mbase + rt * 16 + (lane >> 4) * 4;
            float tv = ts[sl];
#pragma unroll
            for (int reg = 0; reg < 4; ++reg) {
                size_t idx = boff + (size_t)(r0 + reg) * HWn + s;
                float g = dacc[rt][ct][reg] - Zb[idx] * tv;
                wout[idx] = g;
#pragma unroll
                for (int j = 0; j <= K; ++j) {
                    float u = b2f(Qb[(size_t)j * NTOT + idx]);
                    pd[j] = fmaf(u, g, pd[j]);
                }
            }
        }
#pragma unroll
    for (int j = 0; j <= K; ++j) {
        float q = pd[j];
        for (int o2 = 32; o2 > 0; o2 >>= 1) q += __shfl_down(q, o2);
        if (lane == 0) redd[wq][j] = q;
    }
    __syncthreads();
    if (tid <= K)
        atomicAdd(&acc[(K * 8 + tid) * 8 + b],
                  redd[0][tid] + redd[1][tid] + redd[2][tid] + redd[3][tid]);
}

// ---------------- expm of 9x9 per batch (fp64); emits combine coeffs ----------
__global__ __launch_bounds__(128) void expm_kernel(const float* __restrict__ acc,
                                                   float* __restrict__ coordsOut) {
    __shared__ double Am[81], Pm[81], Tm[81];
    __shared__ double ssc;
    __shared__ int sn;
    const int b = blockIdx.x;
    const int t = threadIdx.x;
    const int r = t / 9, c = t % 9;
    double m[8];
    m[0] = sqrt((double)acc[512 + b]);
    for (int j = 1; j < 8; ++j) m[j] = sqrt((double)acc[512 + j * 8 + b]) + 1e-12 * m[j - 1];
    if (t < 81) {
        double val = 0.0;
        if (r < 8 && c < 8) {
            if (r <= c) val = TEND * (double)acc[(c * 8 + r) * 8 + b] / (m[r] * m[c]);
            else if (r == c + 1) val = TEND * sqrt((double)acc[512 + r * 8 + b]) / m[c];
        }
        if (r == 0 && c == 8) val = TEND;
        Am[t] = val;
    }
    __syncthreads();
    if (t == 0) {
        double mx = 0.0;
        for (int rr = 0; rr < 9; ++rr) {
            double s = 0.0;
            for (int cc = 0; cc < 9; ++cc) s += fabs(Am[rr * 9 + cc]);
            if (s > mx) mx = s;
        }
        int n = 0;
        while (mx > 0.25 && n < 48) { mx *= 0.5; ++n; }
        double sc = 1.0;
        for (int ii = 0; ii < n; ++ii) sc *= 0.5;
        sn = n; ssc = sc;
    }
    __syncthreads();
    if (t < 81) Am[t] *= ssc;
    __syncthreads();
    if (t < 81) Pm[t] = (r == c) ? 1.0 : 0.0;
    __syncthreads();
    for (int i = 20; i >= 1; --i) {
        if (t < 81) {
            double s = 0.0;
            for (int k = 0; k < 9; ++k) s += Am[r * 9 + k] * Pm[k * 9 + c];
            Tm[t] = ((r == c) ? 1.0 : 0.0) + s / (double)i;
        }
        __syncthreads();
        if (t < 81) Pm[t] = Tm[t];
        __syncthreads();
    }
    int n = sn;
    for (int q = 0; q < n; ++q) {
        if (t < 81) {
            double s = 0.0;
            for (int k = 0; k < 9; ++k) s += Pm[r * 9 + k] * Pm[k * 9 + c];
            Tm[t] = s;
        }
        __syncthreads();
        if (t < 81) Pm[t] = Tm[t];
        __syncthreads();
    }
    if (t < 8) coordsOut[b * 8 + t] = (float)(Pm[t * 9 + 8] * m[0] / m[t]);
}

// ------ out = sum_{j=0..7} coeff_j * U_j (bf16) ------
__global__ __launch_bounds__(256) void combine_kernel(const unsigned short* __restrict__ Qb,
                                                      const float* __restrict__ coords,
                                                      float* __restrict__ out) {
    int b = blockIdx.y;
    const size_t boff = (size_t)b * FB;
    float cf[8];
#pragma unroll
    for (int j = 0; j < 8; ++j) cf[j] = coords[b * 8 + j];
    const uint4* uv[8];
#pragma unroll
    for (int j = 0; j < 8; ++j)
        uv[j] = (const uint4*)(Qb + (size_t)j * NTOT + boff);
    int i = blockIdx.x * 256 + threadIdx.x;   // grid.x=128
    float4* ov = (float4*)(out + boff);
#pragma unroll
    for (int r = 0; r < 4; ++r) {
        int idx = i + r * 32768;
        uint4 u[8];
#pragma unroll
        for (int j = 0; j < 8; ++j) u[j] = uv[j][idx];
        float a[8] = {0.f, 0.f, 0.f, 0.f, 0.f, 0.f, 0.f, 0.f};
#pragma unroll
        for (int j = 0; j < 8; ++j) {
            float ue[8]; unp8(u[j], ue);
#pragma unroll
            for (int e = 0; e < 8; ++e) a[e] = fmaf(cf[j], ue[e], a[e]);
        }
        float4 o0 = {a[0], a[1], a[2], a[3]};
        float4 o1 = {a[4], a[5], a[6], a[7]};
        ov[2 * idx] = o0; ov[2 * idx + 1] = o1;
    }
}

extern "C" void kernel_launch(void* const* d_in, const int* in_sizes, int n_in,
                              void* d_out, int out_size, void* d_ws, size_t ws_size,
                              hipStream_t stream) {
    const float* s0 = (const float*)d_in[0];
    const float* v  = (const float*)d_in[1];
    const float* W  = (const float*)d_in[2];
    float* out = (float*)d_out;

    // ws (floats): [acc 576|coords 64|pad->1024 | Whs 32768 | Wls 32768 | Z NTOT | Qb bf16 8*NTOT/2]
    float* ws     = (float*)d_ws;
    float* acc    = ws;
    float* coords = ws + 576;
    unsigned short* Whs = (unsigned short*)(ws + 1024);
    unsigned short* Wls = (unsigned short*)(ws + 1024 + 32768);
    float* Zb     = ws + 1024 + 65536;
    unsigned short* Qb = (unsigned short*)(Zb + NTOT);   // U_0..U_7 bf16 (134 MB)
    float* w      = out;   // working A-output (fp32)

    init_kernel<<<dim3(1), dim3(256), 0, stream>>>(ws);
    wsplit_kernel<<<dim3(8, 16), dim3(64), 0, stream>>>(W, Whs, Wls);

    dim3 blk(256), gs(128, 8), ga(64, 8);
    v2bf_kernel<<<gs, blk, 0, stream>>>(v, Qb, acc);
    z_kernel<<<ga, blk, 0, stream>>>(s0, Whs, Wls, Zb);

    fused_step<0><<<ga, blk, 0, stream>>>(w, Qb, s0, Whs, Wls, Zb, w, acc);
    fused_step<1><<<ga, blk, 0, stream>>>(w, Qb, s0, Whs, Wls, Zb, w, acc);
    fused_step<2><<<ga, blk, 0, stream>>>(w, Qb, s0, Whs, Wls, Zb, w, acc);
    fused_step<3><<<ga, blk, 0, stream>>>(w, Qb, s0, Whs, Wls, Zb, w, acc);
    fused_step<4><<<ga, blk, 0, stream>>>(w, Qb, s0, Whs, Wls, Zb, w, acc);
    fused_step<5><<<ga, blk, 0, stream>>>(w, Qb, s0, Whs, Wls, Zb, w, acc);
    fused_step<6><<<ga, blk, 0, stream>>>(w, Qb, s0, Whs, Wls, Zb, w, acc);
    fused_step<7><<<ga, blk, 0, stream>>>(w, Qb, s0, Whs, Wls, Zb, w, acc);

    expm_kernel<<<dim3(8), dim3(128), 0, stream>>>(acc, coords);
    combine_kernel<<<gs, blk, 0, stream>>>(Qb, coords, out);
}